// Round 7
// baseline (203.159 us; speedup 1.0000x reference)
//
#include <hip/hip_runtime.h>
#include <hip/hip_bf16.h>
#include <math.h>

// Shapes: B=8, T1=512, T2=128, LA=128, E=64, G=3E=192, DL=256
#define Bn 8
#define T1n 512
#define T2n 128
#define En 64
#define Gn 192
#define DLn 256
#define XGP 204   // padded LDS row (bf16 elems)

typedef __attribute__((ext_vector_type(8))) short short8;
typedef __attribute__((ext_vector_type(4))) float float4v;

__device__ __forceinline__ float fast_rcp(float x) { return __builtin_amdgcn_rcpf(x); }

// round-to-nearest-even f32 -> bf16 bits
__device__ __forceinline__ unsigned short f32_to_bf16(float v) {
    unsigned u = __builtin_bit_cast(unsigned, v);
    u += 0x7FFFu + ((u >> 16) & 1u);
    return (unsigned short)(u >> 16);
}
__device__ __forceinline__ float bf16_to_f32(unsigned short s) {
    unsigned u = ((unsigned)s) << 16;
    return __builtin_bit_cast(float, u);
}

// ---------------------------------------------------------------------------
// K3: self-contained GRU scan. 16 blocks = (b, dir), ONE wave (64 threads).
// Phase 1: xg = emb(cs) @ K + b[0] via MFMA, stored bf16 in LDS (padded rows).
// Phase 2: 128-step scan. Per step:
//   - h fragments via 2x ds_read_b128 (the only on-chain LDS dependency)
//   - xg for step s+1 prefetched into registers (3x ds_read_u16 issued after
//     the b128s; latency hides under MFMA+gates; in-order DS pipe means they
//     never delay the h reads)
//   - h.R via 24 INDEPENDENT MFMAs (two K-tiles combined by a VALU add at
//     select time -> no chained-MFMA latency)
// Single-wave: no barriers; LDS ordering via in-order DS + lgkmcnt.
// ---------------------------------------------------------------------------
__global__ __launch_bounds__(64) void k_scan(const int* __restrict__ char_seq,
                                             const float* __restrict__ emb_table,
                                             const float* __restrict__ Kf,
                                             const float* __restrict__ bf,
                                             const float* __restrict__ Kb,
                                             const float* __restrict__ bb,
                                             const float* __restrict__ Rf,
                                             const float* __restrict__ Rb,
                                             float* __restrict__ ctx) {
    int blk = blockIdx.x;             // 0..15
    int b = blk & 7, d = blk >> 3;
    int lane = threadIdx.x;           // 0..63
    int quad = lane >> 4, col = lane & 15;

    const float* Km   = d ? Kb : Kf;
    const float* bias = d ? bb : bf;  // [2][192]
    const float* R    = d ? Rb : Rf;

    // mask bits in SGPRs
    unsigned long long mlo = __ballot(char_seq[b * T2n + lane] != 0);
    unsigned long long mhi = __ballot(char_seq[b * T2n + 64 + lane] != 0);

    __shared__ unsigned short xg_l[T2n * XGP];        // ~51 KB
    __shared__ __align__(16) unsigned short hb[En];   // h in bf16, 128 B

    // fragment array reused: K (phase 1) then R (phase 2) -> caps VGPRs
    short8 frag[12][2];

    // ---------------- phase 1: xg into LDS ----------------
    {
        #pragma unroll
        for (int nt = 0; nt < 12; ++nt)
            #pragma unroll
            for (int kt = 0; kt < 2; ++kt) {
                short8 f;
                #pragma unroll
                for (int j = 0; j < 8; ++j)
                    f[j] = (short)f32_to_bf16(Km[(kt * 32 + quad * 8 + j) * Gn + nt * 16 + col]);
                frag[nt][kt] = f;
            }
        float b0v[12];
        #pragma unroll
        for (int nt = 0; nt < 12; ++nt) b0v[nt] = bias[nt * 16 + col];

        #pragma unroll
        for (int mt = 0; mt < 8; ++mt) {
            int cs = char_seq[b * T2n + mt * 16 + col];
            const float4* e4 = (const float4*)(emb_table + (size_t)cs * En);
            float4 e0 = e4[quad * 2], e1 = e4[quad * 2 + 1];
            float4 e2 = e4[8 + quad * 2], e3 = e4[8 + quad * 2 + 1];
            short8 a0, a1;
            a0[0] = (short)f32_to_bf16(e0.x); a0[1] = (short)f32_to_bf16(e0.y);
            a0[2] = (short)f32_to_bf16(e0.z); a0[3] = (short)f32_to_bf16(e0.w);
            a0[4] = (short)f32_to_bf16(e1.x); a0[5] = (short)f32_to_bf16(e1.y);
            a0[6] = (short)f32_to_bf16(e1.z); a0[7] = (short)f32_to_bf16(e1.w);
            a1[0] = (short)f32_to_bf16(e2.x); a1[1] = (short)f32_to_bf16(e2.y);
            a1[2] = (short)f32_to_bf16(e2.z); a1[3] = (short)f32_to_bf16(e2.w);
            a1[4] = (short)f32_to_bf16(e3.x); a1[5] = (short)f32_to_bf16(e3.y);
            a1[6] = (short)f32_to_bf16(e3.z); a1[7] = (short)f32_to_bf16(e3.w);
            float4v acc[12];
            #pragma unroll
            for (int nt = 0; nt < 12; ++nt) {
                float4v z4 = {0.f, 0.f, 0.f, 0.f};
                z4 = __builtin_amdgcn_mfma_f32_16x16x32_bf16(a1, frag[nt][1], z4, 0, 0, 0);
                acc[nt] = __builtin_amdgcn_mfma_f32_16x16x32_bf16(a0, frag[nt][0], z4, 0, 0, 0);
            }
            #pragma unroll
            for (int nt = 0; nt < 12; ++nt)
                #pragma unroll
                for (int r = 0; r < 4; ++r)
                    xg_l[(mt * 16 + quad * 4 + r) * XGP + nt * 16 + col] =
                        f32_to_bf16(acc[nt][r] + b0v[nt]);
        }
    }

    // ---------------- phase 2: the scan ----------------
    #pragma unroll
    for (int nt = 0; nt < 12; ++nt)
        #pragma unroll
        for (int kt = 0; kt < 2; ++kt) {
            short8 f;
            #pragma unroll
            for (int j = 0; j < 8; ++j)
                f[j] = (short)f32_to_bf16(R[(kt * 32 + quad * 8 + j) * Gn + nt * 16 + col]);
            frag[nt][kt] = f;
        }
    float bz = bias[Gn + lane], br = bias[Gn + En + lane], bh = bias[Gn + 2 * En + lane];

    hb[lane] = 0;
    float hreg = 0.f, y = 0.f;
    float* ctxb = ctx + (size_t)b * T2n * 128 + d * En;
    int i0 = d ? (T2n - 1) : 0;
    int istep = d ? -1 : 1;
    bool q1 = (quad & 1) != 0, q2 = (quad & 2) != 0;
    const short8* ap = (const short8*)hb;

    // prime the xg register pipeline (step 0)
    unsigned short xzc, xrc, xhc;
    {
        int xb = i0 * XGP + lane;
        xzc = xg_l[xb]; xrc = xg_l[xb + 64]; xhc = xg_l[xb + 128];
    }

    for (int step = 0; step < T2n; ++step) {
        int idx = i0 + istep * step;
        // h fragments (the blocking LDS dependency; issued FIRST)
        short8 a0 = ap[quad];
        short8 a1 = ap[4 + quad];
        // prefetch next step's xg into registers (latency hides under MFMAs)
        unsigned short pz, pr, ph;
        {
            int nidx = (step == T2n - 1) ? idx : idx + istep;
            int nb = nidx * XGP + lane;
            pz = xg_l[nb]; pr = xg_l[nb + 64]; ph = xg_l[nb + 128];
        }
        // 12 n-tiles x 2 independent k-tiles (no MFMA chaining)
        float4v accA[12], accB[12];
        #pragma unroll
        for (int nt = 0; nt < 12; ++nt) {
            float4v z4 = {0.f, 0.f, 0.f, 0.f};
            accA[nt] = __builtin_amdgcn_mfma_f32_16x16x32_bf16(a0, frag[nt][0], z4, 0, 0, 0);
            accB[nt] = __builtin_amdgcn_mfma_f32_16x16x32_bf16(a1, frag[nt][1], z4, 0, 0, 0);
        }
        // select this lane's rz/rr/rh (tile nt = g*4+quad, col = lane&15)
        float s0  = accA[0].x + accB[0].x, s1 = accA[1].x + accB[1].x;
        float s2  = accA[2].x + accB[2].x, s3 = accA[3].x + accB[3].x;
        float rz  = (q2 ? (q1 ? s3 : s2) : (q1 ? s1 : s0)) + bz;
        float s4  = accA[4].x + accB[4].x, s5 = accA[5].x + accB[5].x;
        float s6  = accA[6].x + accB[6].x, s7 = accA[7].x + accB[7].x;
        float rr  = (q2 ? (q1 ? s7 : s6) : (q1 ? s5 : s4)) + br;
        float s8  = accA[8].x + accB[8].x, s9 = accA[9].x + accB[9].x;
        float s10 = accA[10].x + accB[10].x, s11 = accA[11].x + accB[11].x;
        float rh  = (q2 ? (q1 ? s11 : s10) : (q1 ? s9 : s8)) + bh;
        // gates (xg from registers, prefetched last iteration)
        float xz = bf16_to_f32(xzc), xr = bf16_to_f32(xrc), xh = bf16_to_f32(xhc);
        float z = fast_rcp(1.f + __expf(-(xz + rz)));
        float r = fast_rcp(1.f + __expf(-(xr + rr)));
        float a = xh + r * rh;
        float hh = 1.f - 2.f * fast_rcp(1.f + __expf(2.f * a));
        float hn = hh + z * (hreg - hh);
        bool m = (idx < 64) ? ((mlo >> idx) & 1ull) : ((mhi >> (idx - 64)) & 1ull);
        if (m) { hreg = hn; y = hn; }
        ctxb[idx * 128 + lane] = y;       // fire-and-forget global store
        hb[lane] = f32_to_bf16(hreg);     // same-wave LDS; lgkmcnt-ordered
        xzc = pz; xrc = pr; xhc = ph;
    }
}

// ---------------------------------------------------------------------------
// K4: per (b,s): P0/P1 = ctx_row @ W1[tap], then
//   A = P0@W20, Cm = P1@W21, Bm = P1@W20 + P0@W21, sC = ctx_row . w_c,
//   plus 4 sL dot-products per block.
// ---------------------------------------------------------------------------
__global__ __launch_bounds__(128) void k_ctxw(const float* __restrict__ ctx,
                                              const float* __restrict__ conv1_w,
                                              const float* __restrict__ conv2_w,
                                              const float* __restrict__ w_char,
                                              const float* __restrict__ lstm,
                                              float* __restrict__ Am,
                                              float* __restrict__ Bm,
                                              float* __restrict__ Cm,
                                              float* __restrict__ sC,
                                              float* __restrict__ sL) {
    int bs = blockIdx.x;              // b*128+s
    int tid = threadIdx.x;            // 0..127
    {
        int wv = tid >> 6, lane = tid & 63;
        const float4* wl = (const float4*)w_char;
        #pragma unroll
        for (int q = 0; q < 2; ++q) {
            int bt = bs * 4 + wv * 2 + q;
            const float4* row = (const float4*)(lstm + (size_t)bt * DLn);
            float4 r4 = row[lane];
            float4 w4 = wl[lane];
            float s = r4.x * w4.x + r4.y * w4.y + r4.z * w4.z + r4.w * w4.w;
            #pragma unroll
            for (int off = 32; off; off >>= 1) s += __shfl_down(s, off);
            if (lane == 0) sL[bt] = s;
        }
    }
    __shared__ float crow[128];
    __shared__ float p0[En], p1[En];
    crow[tid] = ctx[(size_t)bs * 128 + tid];
    __syncthreads();
    if (tid < 64) {
        float s = crow[tid] * w_char[DLn + tid] + crow[64 + tid] * w_char[DLn + 64 + tid];
        #pragma unroll
        for (int off = 32; off; off >>= 1) s += __shfl_down(s, off);
        if (tid == 0) sC[bs] = s;
    }
    int tap = tid >> 6, o = tid & 63;
    const float* W = conv1_w + tap * 128 * En;
    float acc = 0.f;
    #pragma unroll
    for (int c = 0; c < 128; ++c) acc = fmaf(crow[c], W[c * En + o], acc);
    if (tap == 0) p0[o] = acc; else p1[o] = acc;
    __syncthreads();
    const float* W20 = conv2_w;            // [64][64]
    const float* W21 = conv2_w + En * En;
    if (tid < 64) {
        float a = 0.f, cm = 0.f;
        #pragma unroll
        for (int c = 0; c < En; ++c) {
            a  = fmaf(p0[c], W20[c * En + tid], a);
            cm = fmaf(p1[c], W21[c * En + tid], cm);
        }
        Am[(size_t)bs * En + tid] = a;
        Cm[(size_t)bs * En + tid] = cm;
    } else {
        int o2 = tid - 64;
        float bacc = 0.f;
        #pragma unroll
        for (int c = 0; c < En; ++c) {
            bacc = fmaf(p1[c], W20[c * En + o2], bacc);
            bacc = fmaf(p0[c], W21[c * En + o2], bacc);
        }
        Bm[(size_t)bs * En + o2] = bacc;
    }
}

// ---------------------------------------------------------------------------
// K5: per (b, 8-t tile): score rows -> char_weights; then
//   fe[b,t,o] = max_s ( sc[s]*A[s,o] + sc[s+1]*Bm[s+1,o] + sc[s+2]*Cm[s+2,o] + bb2[o] )
// ---------------------------------------------------------------------------
__global__ __launch_bounds__(128) void k_final(const float* __restrict__ sL,
                                               const float* __restrict__ sC,
                                               const float* __restrict__ w_char,
                                               const float* __restrict__ b_char,
                                               const float* __restrict__ conv1_b,
                                               const float* __restrict__ conv2_w,
                                               const float* __restrict__ conv2_b,
                                               const float* __restrict__ Am,
                                               const float* __restrict__ Bm,
                                               const float* __restrict__ Cm,
                                               float* __restrict__ fe,
                                               float* __restrict__ cw) {
    int blk = blockIdx.x;             // b(3b) x ttile(6b)
    int b = blk >> 6, ttile = blk & 63;
    int t0 = ttile * 8;
    int tid = threadIdx.x;            // 0..127
    float w_t = w_char[DLn + 128], w_i = w_char[DLn + 129], bc = b_char[0];
    __shared__ float sc8[8][T2n];
    {
        int s = tid;
        float sCs = sC[b * T2n + s] + w_i * (float)s + bc;
        #pragma unroll
        for (int tt = 0; tt < 8; ++tt) {
            int t = t0 + tt;
            float v = sL[b * T1n + t] + sCs + w_t * (float)t;
            sc8[tt][s] = v;
            cw[((size_t)(b * T1n + t)) * T2n + s] = v;
        }
    }
    int o = tid & 63, p = tid >> 6;
    float bb2 = conv2_b[o];
    #pragma unroll
    for (int c = 0; c < En; ++c)
        bb2 += conv1_b[c] * (conv2_w[c * En + o] + conv2_w[En * En + c * En + o]);
    __syncthreads();

    float acc[8];
    #pragma unroll
    for (int tt = 0; tt < 8; ++tt) acc[tt] = -__builtin_inff();
    const float* Ab = Am + (size_t)(b * T2n) * En + o;
    const float* Bb = Bm + (size_t)(b * T2n) * En + o;
    const float* Cb = Cm + (size_t)(b * T2n) * En + o;
    for (int s = p; s < T2n - 2; s += 2) {
        float a  = Ab[s * En];
        float bm = Bb[(s + 1) * En];
        float cm = Cb[(s + 2) * En];
        #pragma unroll
        for (int tt = 0; tt < 8; ++tt) {
            float v = fmaf(sc8[tt][s], a,
                      fmaf(sc8[tt][s + 1], bm,
                      fmaf(sc8[tt][s + 2], cm, bb2)));
            acc[tt] = fmaxf(acc[tt], v);
        }
    }
    __shared__ float red[64][9];
    if (p == 1) {
        #pragma unroll
        for (int tt = 0; tt < 8; ++tt) red[o][tt] = acc[tt];
    }
    __syncthreads();
    if (p == 0) {
        #pragma unroll
        for (int tt = 0; tt < 8; ++tt) {
            float v = fmaxf(acc[tt], red[o][tt]);
            fe[((size_t)(b * T1n + t0 + tt)) * En + o] = v;
        }
    }
}

// ---------------------------------------------------------------------------
extern "C" void kernel_launch(void* const* d_in, const int* in_sizes, int n_in,
                              void* d_out, int out_size, void* d_ws, size_t ws_size,
                              hipStream_t stream) {
    const float* lstm      = (const float*)d_in[0];
    const int*   char_seq  = (const int*)d_in[1];
    const float* emb_table = (const float*)d_in[2];
    const float* Kf        = (const float*)d_in[3];
    const float* Rf        = (const float*)d_in[4];
    const float* bf        = (const float*)d_in[5];
    const float* Kb        = (const float*)d_in[6];
    const float* Rb        = (const float*)d_in[7];
    const float* bb        = (const float*)d_in[8];
    const float* w_char    = (const float*)d_in[9];
    const float* b_char    = (const float*)d_in[10];
    const float* conv1_w   = (const float*)d_in[11];
    const float* conv1_b   = (const float*)d_in[12];
    const float* conv2_w   = (const float*)d_in[13];
    const float* conv2_b   = (const float*)d_in[14];

    float* out = (float*)d_out;
    float* fe = out;                             // 8*512*64 = 262144
    float* cw = out + Bn * T1n * En;             // 8*512*128 = 524288

    float* ws  = (float*)d_ws;
    float* ctx = ws;                             // 8*128*128 = 131072
    float* sC  = ctx + Bn * T2n * 128;           // 1024
    float* sL  = sC + Bn * T2n;                  // 4096
    float* Am  = sL + Bn * T1n;                  // 65536
    float* Bm  = Am + Bn * T2n * En;             // 65536
    float* Cm  = Bm + Bn * T2n * En;             // 65536

    k_scan<<<16, 64, 0, stream>>>(char_seq, emb_table, Kf, bf, Kb, bb, Rf, Rb, ctx);
    k_ctxw<<<Bn * T2n, 128, 0, stream>>>(ctx, conv1_w, conv2_w, w_char, lstm,
                                         Am, Bm, Cm, sC, sL);
    k_final<<<(Bn * T1n) / 8, 128, 0, stream>>>(sL, sC, w_char, b_char, conv1_b,
                                                conv2_w, conv2_b, Am, Bm, Cm, fe, cw);
}

// Round 8
// 167.869 us; speedup vs baseline: 1.2102x; 1.2102x over previous
//
#include <hip/hip_runtime.h>
#include <hip/hip_bf16.h>
#include <math.h>

// Shapes: B=8, T1=512, T2=128, LA=128, E=64, G=3E=192, DL=256
#define Bn 8
#define T1n 512
#define T2n 128
#define En 64
#define Gn 192
#define DLn 256

typedef __attribute__((ext_vector_type(8))) short short8;
typedef __attribute__((ext_vector_type(4))) float float4v;

__device__ __forceinline__ float fast_rcp(float x) { return __builtin_amdgcn_rcpf(x); }

// round-to-nearest-even f32 -> bf16 bits
__device__ __forceinline__ unsigned short f32_to_bf16(float v) {
    unsigned u = __builtin_bit_cast(unsigned, v);
    u += 0x7FFFu + ((u >> 16) & 1u);
    return (unsigned short)(u >> 16);
}
__device__ __forceinline__ float bf16_to_f32(unsigned short s) {
    unsigned u = ((unsigned)s) << 16;
    return __builtin_bit_cast(float, u);
}

// async global->LDS, 16 B per lane (dest = wave-uniform base + lane*16)
__device__ __forceinline__ void load_lds16(const void* g, void* l) {
    __builtin_amdgcn_global_load_lds(
        (const __attribute__((address_space(1))) unsigned int*)g,
        (__attribute__((address_space(3))) unsigned int*)l, 16, 0, 0);
}

// ---------------------------------------------------------------------------
// K1: xg[d][b][t][j] = bf16( b_d[0][j] + emb(cs[b][t]) . K_d[:,j] )
// grid: 1024 blocks x 384 threads (2 dirs x 192 gates). Massively parallel;
// keeps the ugly emb gather OFF the scan's critical path.
// ---------------------------------------------------------------------------
__global__ __launch_bounds__(384) void k_pre(const int* __restrict__ char_seq,
                                             const float* __restrict__ emb_table,
                                             const float* __restrict__ Kf,
                                             const float* __restrict__ bf,
                                             const float* __restrict__ Kb,
                                             const float* __restrict__ bb,
                                             unsigned short* __restrict__ xgbf) {
    int bt = blockIdx.x;              // 0..1023
    int b = bt >> 7, t = bt & 127;
    int tid = threadIdx.x;            // 0..383
    __shared__ __align__(16) float emb[En];
    if (tid < En) {
        int cs = char_seq[b * T2n + t];
        emb[tid] = emb_table[cs * En + tid];
    }
    __syncthreads();
    int d = tid / Gn;                 // wave-uniform
    int j = tid - d * Gn;
    const float* K = d ? Kb : Kf;
    const float* bias = d ? bb : bf;  // row 0
    float acc = bias[j];
    #pragma unroll
    for (int e = 0; e < En; ++e) acc = fmaf(emb[e], K[e * Gn + j], acc);
    xgbf[((size_t)(d * Bn + b) * T2n + t) * Gn + j] = f32_to_bf16(acc);
}

// ---------------------------------------------------------------------------
// K3: GRU scan. 16 blocks = (b, dir), ONE wave (64 threads).
// Stage: 48 KB of bf16 xg -> LDS via global_load_lds (48 issues, 1 wait).
// Loop (zero global loads): h frags via 2x ds_read_b128; xg via 3 u16 LDS
// reads queued behind them (in-order DS pipe, ready before gates need them);
// h.R via 12 chained MFMA pairs (C = hoisted constant zero); gates via
// fast exp/rcp; mask from SGPR ballots; ctx store fire-and-forget.
// ---------------------------------------------------------------------------
__global__ __launch_bounds__(64) void k_scan(const unsigned short* __restrict__ xgbf,
                                             const float* __restrict__ Rf,
                                             const float* __restrict__ bf,
                                             const float* __restrict__ Rb,
                                             const float* __restrict__ bb,
                                             const int* __restrict__ char_seq,
                                             float* __restrict__ ctx) {
    int blk = blockIdx.x;             // 0..15
    int b = blk & 7, d = blk >> 3;
    int lane = threadIdx.x;           // 0..63
    int quad = lane >> 4, col = lane & 15;

    __shared__ __align__(16) unsigned short xg_l[T2n * Gn];   // 48 KB
    __shared__ __align__(16) unsigned short hb[En];           // 128 B

    // kick off the async xg staging first (48 x 1 KB, fire-and-forget)
    {
        const unsigned char* gb = (const unsigned char*)(xgbf + (size_t)(d * Bn + b) * T2n * Gn);
        unsigned char* lb = (unsigned char*)xg_l;
        #pragma unroll
        for (int i = 0; i < 48; ++i)
            load_lds16(gb + i * 1024 + lane * 16, lb + i * 1024 + lane * 16);
    }

    // overlap: ballots, R fragments, biases while staging is in flight
    unsigned long long mlo = __ballot(char_seq[b * T2n + lane] != 0);
    unsigned long long mhi = __ballot(char_seq[b * T2n + 64 + lane] != 0);

    const float* R = d ? Rb : Rf;
    const float* bias = d ? bb : bf;
    short8 frag[12][2];
    #pragma unroll
    for (int nt = 0; nt < 12; ++nt)
        #pragma unroll
        for (int kt = 0; kt < 2; ++kt) {
            short8 f;
            #pragma unroll
            for (int j = 0; j < 8; ++j)
                f[j] = (short)f32_to_bf16(R[(kt * 32 + quad * 8 + j) * Gn + nt * 16 + col]);
            frag[nt][kt] = f;
        }
    float bz = bias[Gn + lane], br = bias[Gn + En + lane], bh = bias[Gn + 2 * En + lane];

    hb[lane] = 0;
    float hreg = 0.f, y = 0.f;
    float* ctxb = ctx + (size_t)b * T2n * 128 + d * En;
    int i0 = d ? (T2n - 1) : 0;
    int istep = d ? -1 : 1;
    bool q1 = (quad & 1) != 0, q2 = (quad & 2) != 0;
    const short8* ap = (const short8*)hb;

    // wait for staging to land before the loop reads xg_l
    asm volatile("s_waitcnt vmcnt(0)" ::: "memory");

    for (int step = 0; step < T2n; ++step) {
        int idx = i0 + istep * step;
        // h fragments first (the loop-carried LDS dependency)
        short8 a0 = ap[quad];
        short8 a1 = ap[4 + quad];
        // xg reads queue behind them; needed only after the MFMAs
        int xb = idx * Gn + lane;
        unsigned short xzs = xg_l[xb];
        unsigned short xrs = xg_l[xb + 64];
        unsigned short xhs = xg_l[xb + 128];
        // 12 n-tiles, 2 chained k-tiles each (C=0 is a hoisted constant)
        float4v z4 = {0.f, 0.f, 0.f, 0.f};
        float4v acc[12];
        #pragma unroll
        for (int nt = 0; nt < 12; ++nt) {
            float4v p = __builtin_amdgcn_mfma_f32_16x16x32_bf16(a0, frag[nt][0], z4, 0, 0, 0);
            acc[nt] = __builtin_amdgcn_mfma_f32_16x16x32_bf16(a1, frag[nt][1], p, 0, 0, 0);
        }
        // select this lane's rz/rr/rh (gate col j = nt*16+col, nt = g*4+quad)
        float rz = (q2 ? (q1 ? acc[3].x : acc[2].x) : (q1 ? acc[1].x : acc[0].x)) + bz;
        float rr = (q2 ? (q1 ? acc[7].x : acc[6].x) : (q1 ? acc[5].x : acc[4].x)) + br;
        float rh = (q2 ? (q1 ? acc[11].x : acc[10].x) : (q1 ? acc[9].x : acc[8].x)) + bh;
        // gates
        float xz = bf16_to_f32(xzs), xr = bf16_to_f32(xrs), xh = bf16_to_f32(xhs);
        float z = fast_rcp(1.f + __expf(-(xz + rz)));
        float r = fast_rcp(1.f + __expf(-(xr + rr)));
        float a = xh + r * rh;
        float hh = 1.f - 2.f * fast_rcp(1.f + __expf(2.f * a));
        float hn = hh + z * (hreg - hh);
        bool m = (idx < 64) ? ((mlo >> idx) & 1ull) : ((mhi >> (idx - 64)) & 1ull);
        if (m) { hreg = hn; y = hn; }
        ctxb[idx * 128 + lane] = y;       // fire-and-forget global store
        hb[lane] = f32_to_bf16(hreg);     // same-wave LDS; lgkmcnt-ordered
    }
}

// ---------------------------------------------------------------------------
// K4: per (b,s): P0/P1 = ctx_row @ W1[tap], then
//   A = P0@W20, Cm = P1@W21, Bm = P1@W20 + P0@W21, sC = ctx_row . w_c,
//   plus 4 sL dot-products per block.
// ---------------------------------------------------------------------------
__global__ __launch_bounds__(128) void k_ctxw(const float* __restrict__ ctx,
                                              const float* __restrict__ conv1_w,
                                              const float* __restrict__ conv2_w,
                                              const float* __restrict__ w_char,
                                              const float* __restrict__ lstm,
                                              float* __restrict__ Am,
                                              float* __restrict__ Bm,
                                              float* __restrict__ Cm,
                                              float* __restrict__ sC,
                                              float* __restrict__ sL) {
    int bs = blockIdx.x;              // b*128+s
    int tid = threadIdx.x;            // 0..127
    {
        int wv = tid >> 6, lane = tid & 63;
        const float4* wl = (const float4*)w_char;
        #pragma unroll
        for (int q = 0; q < 2; ++q) {
            int bt = bs * 4 + wv * 2 + q;
            const float4* row = (const float4*)(lstm + (size_t)bt * DLn);
            float4 r4 = row[lane];
            float4 w4 = wl[lane];
            float s = r4.x * w4.x + r4.y * w4.y + r4.z * w4.z + r4.w * w4.w;
            #pragma unroll
            for (int off = 32; off; off >>= 1) s += __shfl_down(s, off);
            if (lane == 0) sL[bt] = s;
        }
    }
    __shared__ float crow[128];
    __shared__ float p0[En], p1[En];
    crow[tid] = ctx[(size_t)bs * 128 + tid];
    __syncthreads();
    if (tid < 64) {
        float s = crow[tid] * w_char[DLn + tid] + crow[64 + tid] * w_char[DLn + 64 + tid];
        #pragma unroll
        for (int off = 32; off; off >>= 1) s += __shfl_down(s, off);
        if (tid == 0) sC[bs] = s;
    }
    int tap = tid >> 6, o = tid & 63;
    const float* W = conv1_w + tap * 128 * En;
    float acc = 0.f;
    #pragma unroll
    for (int c = 0; c < 128; ++c) acc = fmaf(crow[c], W[c * En + o], acc);
    if (tap == 0) p0[o] = acc; else p1[o] = acc;
    __syncthreads();
    const float* W20 = conv2_w;            // [64][64]
    const float* W21 = conv2_w + En * En;
    if (tid < 64) {
        float a = 0.f, cm = 0.f;
        #pragma unroll
        for (int c = 0; c < En; ++c) {
            a  = fmaf(p0[c], W20[c * En + tid], a);
            cm = fmaf(p1[c], W21[c * En + tid], cm);
        }
        Am[(size_t)bs * En + tid] = a;
        Cm[(size_t)bs * En + tid] = cm;
    } else {
        int o2 = tid - 64;
        float bacc = 0.f;
        #pragma unroll
        for (int c = 0; c < En; ++c) {
            bacc = fmaf(p1[c], W20[c * En + o2], bacc);
            bacc = fmaf(p0[c], W21[c * En + o2], bacc);
        }
        Bm[(size_t)bs * En + o2] = bacc;
    }
}

// ---------------------------------------------------------------------------
// K5: per (b, 8-t tile): score rows -> char_weights; then
//   fe[b,t,o] = max_s ( sc[s]*A[s,o] + sc[s+1]*Bm[s+1,o] + sc[s+2]*Cm[s+2,o] + bb2[o] )
// ---------------------------------------------------------------------------
__global__ __launch_bounds__(128) void k_final(const float* __restrict__ sL,
                                               const float* __restrict__ sC,
                                               const float* __restrict__ w_char,
                                               const float* __restrict__ b_char,
                                               const float* __restrict__ conv1_b,
                                               const float* __restrict__ conv2_w,
                                               const float* __restrict__ conv2_b,
                                               const float* __restrict__ Am,
                                               const float* __restrict__ Bm,
                                               const float* __restrict__ Cm,
                                               float* __restrict__ fe,
                                               float* __restrict__ cw) {
    int blk = blockIdx.x;             // b(3b) x ttile(6b)
    int b = blk >> 6, ttile = blk & 63;
    int t0 = ttile * 8;
    int tid = threadIdx.x;            // 0..127
    float w_t = w_char[DLn + 128], w_i = w_char[DLn + 129], bc = b_char[0];
    __shared__ float sc8[8][T2n];
    {
        int s = tid;
        float sCs = sC[b * T2n + s] + w_i * (float)s + bc;
        #pragma unroll
        for (int tt = 0; tt < 8; ++tt) {
            int t = t0 + tt;
            float v = sL[b * T1n + t] + sCs + w_t * (float)t;
            sc8[tt][s] = v;
            cw[((size_t)(b * T1n + t)) * T2n + s] = v;
        }
    }
    int o = tid & 63, p = tid >> 6;
    float bb2 = conv2_b[o];
    #pragma unroll
    for (int c = 0; c < En; ++c)
        bb2 += conv1_b[c] * (conv2_w[c * En + o] + conv2_w[En * En + c * En + o]);
    __syncthreads();

    float acc[8];
    #pragma unroll
    for (int tt = 0; tt < 8; ++tt) acc[tt] = -__builtin_inff();
    const float* Ab = Am + (size_t)(b * T2n) * En + o;
    const float* Bb = Bm + (size_t)(b * T2n) * En + o;
    const float* Cb = Cm + (size_t)(b * T2n) * En + o;
    for (int s = p; s < T2n - 2; s += 2) {
        float a  = Ab[s * En];
        float bm = Bb[(s + 1) * En];
        float cm = Cb[(s + 2) * En];
        #pragma unroll
        for (int tt = 0; tt < 8; ++tt) {
            float v = fmaf(sc8[tt][s], a,
                      fmaf(sc8[tt][s + 1], bm,
                      fmaf(sc8[tt][s + 2], cm, bb2)));
            acc[tt] = fmaxf(acc[tt], v);
        }
    }
    __shared__ float red[64][9];
    if (p == 1) {
        #pragma unroll
        for (int tt = 0; tt < 8; ++tt) red[o][tt] = acc[tt];
    }
    __syncthreads();
    if (p == 0) {
        #pragma unroll
        for (int tt = 0; tt < 8; ++tt) {
            float v = fmaxf(acc[tt], red[o][tt]);
            fe[((size_t)(b * T1n + t0 + tt)) * En + o] = v;
        }
    }
}

// ---------------------------------------------------------------------------
extern "C" void kernel_launch(void* const* d_in, const int* in_sizes, int n_in,
                              void* d_out, int out_size, void* d_ws, size_t ws_size,
                              hipStream_t stream) {
    const float* lstm      = (const float*)d_in[0];
    const int*   char_seq  = (const int*)d_in[1];
    const float* emb_table = (const float*)d_in[2];
    const float* Kf        = (const float*)d_in[3];
    const float* Rf        = (const float*)d_in[4];
    const float* bf        = (const float*)d_in[5];
    const float* Kb        = (const float*)d_in[6];
    const float* Rb        = (const float*)d_in[7];
    const float* bb        = (const float*)d_in[8];
    const float* w_char    = (const float*)d_in[9];
    const float* b_char    = (const float*)d_in[10];
    const float* conv1_w   = (const float*)d_in[11];
    const float* conv1_b   = (const float*)d_in[12];
    const float* conv2_w   = (const float*)d_in[13];
    const float* conv2_b   = (const float*)d_in[14];

    float* out = (float*)d_out;
    float* fe = out;                             // 8*512*64 = 262144
    float* cw = out + Bn * T1n * En;             // 8*512*128 = 524288

    float* ws  = (float*)d_ws;
    unsigned short* xgbf = (unsigned short*)ws;  // 2*8*128*192 u16 = 393216 B
    float* ctx = ws + 98304;                     // 8*128*128 = 131072
    float* sC  = ctx + Bn * T2n * 128;           // 1024
    float* sL  = sC + Bn * T2n;                  // 4096
    float* Am  = sL + Bn * T1n;                  // 65536
    float* Bm  = Am + Bn * T2n * En;             // 65536
    float* Cm  = Bm + Bn * T2n * En;             // 65536

    k_pre <<<Bn * T2n, 384, 0, stream>>>(char_seq, emb_table, Kf, bf, Kb, bb, xgbf);
    k_scan<<<16, 64, 0, stream>>>(xgbf, Rf, bf, Rb, bb, char_seq, ctx);
    k_ctxw<<<Bn * T2n, 128, 0, stream>>>(ctx, conv1_w, conv2_w, w_char, lstm,
                                         Am, Bm, Cm, sC, sL);
    k_final<<<(Bn * T1n) / 8, 128, 0, stream>>>(sL, sC, w_char, b_char, conv1_b,
                                                conv2_w, conv2_b, Am, Bm, Cm, fe, cw);
}